// Round 10
// baseline (230.190 us; speedup 1.0000x reference)
//
#include <hip/hip_runtime.h>

// ---------------------------------------------------------------------------
// Attention forward: out = softmax((X Wq^T + bq)(X Wk^T + bk)^T / 8) (X Wv^T + bv)
// B=2, S=2048, H=1024, NH=16, HD=64.  All matmuls in bf16 MFMA, fp32 accum.
// Round 10: qkv_gemm rewritten LDS-FREE.  Key insight: with the 2x2-wave /
// 4x4-frag decomposition every A/B fragment element is consumed by exactly
// one lane per block -- intra-block LDS reuse was ZERO; cross-block reuse is
// served by L2/L3 anyway.  Direct coalesced global->VGPR fragment loads,
// no barriers, compiler-pipelined vmcnt (AITER-style).  attn unchanged (R9).
// ---------------------------------------------------------------------------

typedef __attribute__((ext_vector_type(8))) short bf16x8;
typedef __attribute__((ext_vector_type(4))) short bf16x4;
typedef __attribute__((ext_vector_type(4))) float f32x4;

#define L2E 1.44269504088896340736f

__device__ __forceinline__ f32x4 mfma16(bf16x4 a, bf16x4 b, f32x4 c) {
#if defined(__AMDGCN__)
  return __builtin_amdgcn_mfma_f32_16x16x16bf16_1k(a, b, c, 0, 0, 0);
#else
  return c;  // host pass never executes device code
#endif
}

__device__ __forceinline__ unsigned short f2bf(float x) {  // RNE
  union { float f; unsigned int u; } a; a.f = x;
  unsigned int r = (a.u + 0x7fffu + ((a.u >> 16) & 1u)) >> 16;
  return (unsigned short)r;
}
__device__ __forceinline__ unsigned int fbits(float x) {
  union { float f; unsigned int u; } a; a.f = x; return a.u;
}

// pack 4 fp32 -> 4 bf16 (A-operand order) with HW packed convert if present
__device__ __forceinline__ bf16x4 pack_bf16x4(float p0, float p1, float p2, float p3) {
#if defined(__AMDGCN__) && __has_builtin(__builtin_amdgcn_cvt_pk_bf16_f32)
  typedef __attribute__((ext_vector_type(2))) __bf16 bf16x2_t;
  union { bf16x2_t h[2]; bf16x4 v; } pk;
  pk.h[0] = __builtin_amdgcn_cvt_pk_bf16_f32(p0, p1);
  pk.h[1] = __builtin_amdgcn_cvt_pk_bf16_f32(p2, p3);
  return pk.v;
#else
  unsigned u0 = fbits(p0) + 0x8000u, u1 = fbits(p1) + 0x8000u;
  unsigned u2 = fbits(p2) + 0x8000u, u3 = fbits(p3) + 0x8000u;
  union { unsigned u[2]; bf16x4 v; } pk;
  pk.u[0] = __builtin_amdgcn_perm(u1, u0, 0x07060302u);
  pk.u[1] = __builtin_amdgcn_perm(u3, u2, 0x07060302u);
  return pk.v;
#endif
}

__device__ __forceinline__ void gl_lds16(const unsigned short* g, unsigned short* l) {
  __builtin_amdgcn_global_load_lds(
      (const __attribute__((address_space(1))) void*)g,
      (__attribute__((address_space(3))) void*)l, 16, 0, 0);
}

// ---------------------------------------------------------------------------
// Kernel 1: fp32 -> bf16 conversion of hidden + the three weight matrices.
// ---------------------------------------------------------------------------
__global__ __launch_bounds__(256) void convert_all(
    const float* __restrict__ hidden, const float* __restrict__ Wq,
    const float* __restrict__ Wk, const float* __restrict__ Wv,
    unsigned short* __restrict__ Xb, unsigned short* __restrict__ Wqb,
    unsigned short* __restrict__ Wkb, unsigned short* __restrict__ Wvb) {
  int i = blockIdx.x * 256 + threadIdx.x;
  const float* src; unsigned short* dst; int off;
  if (i < 1048576)      { src = hidden; dst = Xb;  off = i; }
  else if (i < 1310720) { src = Wq;     dst = Wqb; off = i - 1048576; }
  else if (i < 1572864) { src = Wk;     dst = Wkb; off = i - 1310720; }
  else                  { src = Wv;     dst = Wvb; off = i - 1572864; }
  float4 v = ((const float4*)src)[off];
  ushort4 o;
  o.x = f2bf(v.x); o.y = f2bf(v.y); o.z = f2bf(v.z); o.w = f2bf(v.w);
  ((ushort4*)dst)[off] = o;
}

// ---------------------------------------------------------------------------
// Kernel 2: QKV projection GEMM, LDS-free.  Out[m,n] = sum_k A[m,k]*B[n,k] +b
//   z==0: A=X, B=Wq -> Qh [bh][s][d], pre-scaled L2E/8 (softmax fold)
//   z==1: A=X, B=Wk -> Kh [bh][s][d]
//   z==2: A=Wv, B=X -> Vh [bh][d][s]   (V TRANSPOSED, stores stay coalesced)
// 128x128 block tile, 4 waves in 2x2, each wave 64x64 via 4x4 16x16x32 MFMA.
// Fragments loaded DIRECTLY from global: lane (quad,r) of frag (mi) reads
// 16 B at row (m0+wm*64+mi*16+r), cols [k0+quad*8, +8) -- a wave touches
// 16 rows x 64 B aligned segments (fully coalesced).  No LDS, no barriers;
// compiler software-pipelines loads against MFMAs with fine-grained vmcnt.
// 1D grid of 768; id&7 ~ XCD slab mapping for X L2 residency.
// ---------------------------------------------------------------------------
__global__ __launch_bounds__(256, 3) void qkv_gemm(
    const unsigned short* __restrict__ Xb,
    const unsigned short* __restrict__ Wqb, const unsigned short* __restrict__ Wkb,
    const unsigned short* __restrict__ Wvb,
    const float* __restrict__ bq, const float* __restrict__ bk,
    const float* __restrict__ bv,
    unsigned short* __restrict__ Qh, unsigned short* __restrict__ Kh,
    unsigned short* __restrict__ Vh) {
  const int id  = blockIdx.x;          // 0..767
  const int xcd = id & 7;
  const int j   = id >> 3;             // 0..95
  const int tok = xcd * 4 + (j & 3);   // token tile 0..31
  const int k2  = j >> 2;              // 0..23
  const int ft  = k2 & 7;              // feature tile 0..7
  const int z   = k2 >> 3;             // 0..2

  const unsigned short* Ap; const unsigned short* Bp;
  const float* bias; unsigned short* Out; int m0, n0;
  if (z == 2) {
    Ap = Wvb; Bp = Xb; bias = bv; Out = Vh;
    m0 = ft * 128; n0 = tok * 128;     // m: feature, n: token
  } else {
    Ap = Xb; Bp = (z == 0) ? Wqb : Wkb; bias = (z == 0) ? bq : bk;
    Out = (z == 0) ? Qh : Kh;
    m0 = tok * 128; n0 = ft * 128;     // m: token, n: feature
  }
  const float oscale = (z == 0) ? (0.125f * L2E) : 1.0f;

  const int tid  = threadIdx.x;
  const int lane = tid & 63;
  const int w    = tid >> 6;
  const int wm   = w >> 1, wn = w & 1;
  const int quad = lane >> 4;
  const int r    = lane & 15;

  // per-lane fragment base pointers (16 B contiguous per frag load)
  const unsigned short* abase = Ap + (size_t)(m0 + wm * 64 + r) * 1024 + quad * 8;
  const unsigned short* bbase = Bp + (size_t)(n0 + wn * 64 + r) * 1024 + quad * 8;

  f32x4 acc[4][4];
#pragma unroll
  for (int a = 0; a < 4; a++)
#pragma unroll
    for (int c = 0; c < 4; c++) acc[a][c] = (f32x4){0.f, 0.f, 0.f, 0.f};

#pragma unroll 4
  for (int k0 = 0; k0 < 1024; k0 += 32) {
    bf16x8 a[4], bb[4];
#pragma unroll
    for (int mi = 0; mi < 4; mi++)
      a[mi] = *(const bf16x8*)(abase + mi * 16384 + k0);   // mi*16 rows * 1024
#pragma unroll
    for (int ni = 0; ni < 4; ni++)
      bb[ni] = *(const bf16x8*)(bbase + ni * 16384 + k0);
#pragma unroll
    for (int mi = 0; mi < 4; mi++)
#pragma unroll
      for (int ni = 0; ni < 4; ni++)
        acc[mi][ni] = __builtin_amdgcn_mfma_f32_16x16x32_bf16(a[mi], bb[ni], acc[mi][ni], 0, 0, 0);
  }

  // epilogue: C/D row = quad*4+e, col = r
  if (z == 2) {
#pragma unroll
    for (int mi = 0; mi < 4; mi++)
#pragma unroll
      for (int e = 0; e < 4; e++) {
        int m = m0 + wm * 64 + mi * 16 + quad * 4 + e;  // feature
        float bm = bias[m];
#pragma unroll
        for (int ni = 0; ni < 4; ni++) {
          int n = n0 + wn * 64 + ni * 16 + r;            // token
          int bb2 = n >> 11, s = n & 2047;
          int hh = m >> 6,  d = m & 63;
          float v = acc[mi][ni][e] + bm;
          Out[((size_t)(bb2 * 16 + hh) * 64 + d) * 2048 + s] = f2bf(v);
        }
      }
  } else {
    float biasv[4];
#pragma unroll
    for (int ni = 0; ni < 4; ni++) biasv[ni] = bias[n0 + wn * 64 + ni * 16 + r];
#pragma unroll
    for (int mi = 0; mi < 4; mi++)
#pragma unroll
      for (int ni = 0; ni < 4; ni++)
#pragma unroll
        for (int e = 0; e < 4; e++) {
          int m = m0 + wm * 64 + mi * 16 + quad * 4 + e;  // token
          int n = n0 + wn * 64 + ni * 16 + r;             // feature
          int bb2 = m >> 11, s = m & 2047;
          int hh = n >> 6,  d = n & 63;
          float v = (acc[mi][ni][e] + biasv[ni]) * oscale;
          Out[((size_t)(bb2 * 16 + hh) * 2048 + s) * 64 + d] = f2bf(v);
        }
  }
}

// ---------------------------------------------------------------------------
// Kernel 3: flash attention, in-block split-KV x2, folded static-max softmax,
// register-resident P, ones-MFMA row sums.  (unchanged from round 9)
// 512 threads = 8 waves: group g handles KV rows [g*1024, +1024) of the SAME
// 64-row q-tile; each group has private 16 KB K/V LDS.  Group 1 deposits
// unnormalized acc + l in LDS; group 0 merges and writes normalized output.
// Grid 1024 blocks, 32 KB LDS -> 4 blocks/CU = 32 waves/CU.
// ---------------------------------------------------------------------------
__global__ __launch_bounds__(512, 8) void attn(
    const unsigned short* __restrict__ Qh, const unsigned short* __restrict__ Kh,
    const unsigned short* __restrict__ Vh, float* __restrict__ Out) {
  const int h = blockIdx.y, b = blockIdx.z;
  const int bh = b * 16 + h;
  const int q0 = blockIdx.x * 64;
  const unsigned short* Qp  = Qh + (size_t)bh * 2048 * 64;
  const unsigned short* Kp  = Kh + (size_t)bh * 2048 * 64;
  const unsigned short* VTp = Vh + (size_t)bh * 64 * 2048;   // [d][s]

  __shared__ unsigned short SM[2][2][64 * 64];   // [group][K,V][..]  32 KB

  const int tid  = threadIdx.x;       // 0..511
  const int lane = tid & 63;
  const int w8   = tid >> 6;          // 0..7
  const int half = w8 >> 2;           // KV half
  const int w    = w8 & 3;            // q-subtile
  const int ltid = tid & 255;         // tid within group
  const int quad = lane >> 4;
  const int r    = lane & 15;
  const int rm7  = r & 7;

  unsigned short* Ks  = &SM[half][0][0];
  unsigned short* Vts = &SM[half][1][0];

  // ---- Q fragments direct from global: row q0 + w*16 + r ----
  const unsigned short* qrow = Qp + (size_t)(q0 + w * 16 + r) * 64 + quad * 8;
  bf16x8 aq0 = *(const bf16x8*)(qrow);
  bf16x8 aq1 = *(const bf16x8*)(qrow + 32);

  f32x4 lacc = (f32x4){0.f, 0.f, 0.f, 0.f};   // row-sums of P (C-layout)
  f32x4 acc[4];
#pragma unroll
  for (int dc = 0; dc < 4; dc++) acc[dc] = (f32x4){0.f, 0.f, 0.f, 0.f};
  const f32x4 zero4 = (f32x4){0.f, 0.f, 0.f, 0.f};

  union { unsigned u[2]; bf16x4 v; } ou;
  ou.u[0] = 0x3F803F80u; ou.u[1] = 0x3F803F80u;
  const bf16x4 ones = ou.v;                     // B-frag of 1.0 bf16

  const int kx0 = quad ^ rm7;         // K frag block cols (krow&7 == r&7)
  const int kx1 = (4 + quad) ^ rm7;
  const int qh2 = quad >> 1, ql4 = (quad & 1) * 4;

  const int kvbase = half * 1024;
  for (int kv0 = kvbase; kv0 < kvbase + 1024; kv0 += 64) {
    __syncthreads();
    // ---- stage this group's K (c^(row&7)) and V^T ((src+5*row)&7) tiles ----
#pragma unroll
    for (int i = 0; i < 2; i++) {
      int blk = i * 256 + ltid;
      int row = blk >> 3;
      int cs  = blk & 7;
      gl_lds16(Kp + (size_t)(kv0 + row) * 64 + ((cs ^ (row & 7)) * 8), &Ks[blk * 8]);
      gl_lds16(VTp + (size_t)row * 2048 + kv0 + (((cs + 5 * row) & 7) * 8), &Vts[blk * 8]);
    }
    __syncthreads();

#pragma unroll
    for (int nc = 0; nc < 4; nc++) {
      // K fragments (A operand): rows nc*16 + r
      int krow = nc * 16 + r;
      bf16x8 kf0 = *(const bf16x8*)&Ks[krow * 64 + kx0 * 8];
      bf16x8 kf1 = *(const bf16x8*)&Ks[krow * 64 + kx1 * 8];

      // S^T chunk: lane holds q=r, kv=quad*4+e (already in log2 domain)
      f32x4 t0 = __builtin_amdgcn_mfma_f32_16x16x32_bf16(kf1, aq1, zero4, 0, 0, 0);
      f32x4 sT = __builtin_amdgcn_mfma_f32_16x16x32_bf16(kf0, aq0, t0, 0, 0, 0);

      float p0 = __builtin_exp2f(sT[0]);
      float p1 = __builtin_exp2f(sT[1]);
      float p2 = __builtin_exp2f(sT[2]);
      float p3 = __builtin_exp2f(sT[3]);
      bf16x4 ap = pack_bf16x4(p0, p1, p2, p3);

      // l row-sums on the MFMA pipe (B = ones): D[q][*] = sum_kv P
      lacc = mfma16(ap, ones, lacc);

      // ctx += P V : B frags b64; slot = (2nc + qh2 + 3*vrow) & 7
#pragma unroll
      for (int dc = 0; dc < 4; dc++) {
        int vrow = dc * 16 + r;
        int slot = (2 * nc + qh2 + 3 * vrow) & 7;
        bf16x4 vf = *(const bf16x4*)&Vts[vrow * 64 + slot * 8 + ql4];
        acc[dc] = mfma16(ap, vf, acc[dc]);
      }
    }
  }

  // ---- merge: group 1 -> LDS, group 0 combines and writes ----
  __syncthreads();
  float* Abuf = (float*)&SM[0][0][0];           // 64 q x 65 floats (padded)
  float* Lbuf = Abuf + 64 * 65;                 // 64 floats
  if (half == 1) {
#pragma unroll
    for (int e = 0; e < 4; e++) {
      int q = w * 16 + quad * 4 + e;
#pragma unroll
      for (int dc = 0; dc < 4; dc++)
        Abuf[q * 65 + dc * 16 + r] = acc[dc][e];
      if (r == 0) Lbuf[q] = lacc[e];
    }
  }
  __syncthreads();
  if (half == 0) {
#pragma unroll
    for (int e = 0; e < 4; e++) {
      int q = w * 16 + quad * 4 + e;
      float l = lacc[e] + Lbuf[q];              // total row sum
      float inv = 1.f / l;
      int s = q0 + q;
#pragma unroll
      for (int dc = 0; dc < 4; dc++) {
        int d = dc * 16 + r;
        float v = acc[dc][e] + Abuf[q * 65 + d];
        Out[(size_t)(b * 2048 + s) * 1024 + h * 64 + d] = v * inv;
      }
    }
  }
}

// ---------------------------------------------------------------------------
// Workspace layout (bytes):
//   Qh  @ 0         8388608   [bh][s][d] bf16, pre-scaled L2E/8
//   Kh  @ 8388608   8388608   [bh][s][d] bf16
//   Vh  @ 16777216  8388608   [bh][d][s] bf16 (TRANSPOSED)
//   Xb  @ 25165824  8388608   bf16
//   Wqb @ 33554432  2097152, Wkb @ 35651584, Wvb @ 37748736
//   total 39845888 (~38 MB)
// ---------------------------------------------------------------------------
extern "C" void kernel_launch(void* const* d_in, const int* in_sizes, int n_in,
                              void* d_out, int out_size, void* d_ws, size_t ws_size,
                              hipStream_t stream) {
  const float* hidden = (const float*)d_in[0];
  const float* Wq = (const float*)d_in[1];
  const float* bq = (const float*)d_in[2];
  const float* Wk = (const float*)d_in[3];
  const float* bk = (const float*)d_in[4];
  const float* Wv = (const float*)d_in[5];
  const float* bv = (const float*)d_in[6];
  float* out = (float*)d_out;

  char* ws = (char*)d_ws;
  unsigned short* Qhp = (unsigned short*)(ws + 0);
  unsigned short* Khp = (unsigned short*)(ws + 8388608);
  unsigned short* Vhp = (unsigned short*)(ws + 16777216);
  unsigned short* Xb  = (unsigned short*)(ws + 25165824);
  unsigned short* Wqb = (unsigned short*)(ws + 33554432);
  unsigned short* Wkb = (unsigned short*)(ws + 35651584);
  unsigned short* Wvb = (unsigned short*)(ws + 37748736);

  convert_all<<<7168, 256, 0, stream>>>(hidden, Wq, Wk, Wv, Xb, Wqb, Wkb, Wvb);
  qkv_gemm<<<768, 256, 0, stream>>>(Xb, Wqb, Wkb, Wvb, bq, bk, bv,
                                    Qhp, Khp, Vhp);
  attn<<<dim3(32, 16, 2), 512, 0, stream>>>(Qhp, Khp, Vhp, out);
}